// Round 6
// baseline (250.073 us; speedup 1.0000x reference)
//
#include <hip/hip_runtime.h>
#include <hip/hip_bf16.h>

// LinearAttention: B=4 N=4096 D=1024 H=16 DH=64
// Pipeline:
//  1. convert x -> bf16 ; transpose-convert Wq/Wk/Wv -> Wt[3072][1024] (B^T), Wo -> WoT (+ zero ksum)
//  2. gemm256<0>: qkv = x @ [Wq|Wk|Wv]  (256x256, BK=64, 8 waves, 8-phase counted-vmcnt,
//     hoisted swizzled addressing, T5 setprio). elu+1 on q,k; LDS-staged epilogue:
//       q -> [bh][n][d], k,v -> [bh][d][n]; fused ksum atomics
//  3. kv partials (8-way n-split) + combine
//  4. attn = (q @ kv) / (q . ksum + eps)
//  5. gemm256<1>: out = attn @ Wo + bo

#define DEV_INLINE __device__ __forceinline__

typedef short bf16x8 __attribute__((ext_vector_type(8)));
typedef float f32x4  __attribute__((ext_vector_type(4)));

static constexpr int Bb = 4, Nn = 4096, Dd = 1024, Hh = 16, DHd = 64;
static constexpr int Mrows = Bb * Nn;   // 16384

DEV_INLINE float bf2f(short s) {
  unsigned u = ((unsigned)(unsigned short)s) << 16;
  float f; __builtin_memcpy(&f, &u, 4); return f;
}
DEV_INLINE short f2bf(float f) {
  unsigned u; __builtin_memcpy(&u, &f, 4);
  unsigned r = (u + 0x7fffu + ((u >> 16) & 1u)) >> 16;
  return (short)r;
}

DEV_INLINE void gload16(const void* g, void* l) {
  typedef __attribute__((address_space(1))) const void gv_t;
  typedef __attribute__((address_space(3))) void lv_t;
  __builtin_amdgcn_global_load_lds((gv_t*)g, (lv_t*)l, 16, 0, 0);
}

#define SBAR() __builtin_amdgcn_s_barrier()
#define WAITV(n) asm volatile("s_waitcnt vmcnt(" #n ")" ::: "memory")

// ---------------- 1. conversions ----------------

__global__ void convert_x_kernel(const float* __restrict__ x, short* __restrict__ xb) {
  const int total = Mrows * 1024 / 4;
  for (int i = blockIdx.x * 256 + threadIdx.x; i < total; i += 2048 * 256) {
    float4 v = ((const float4*)x)[i];
    short4 o;
    o.x = f2bf(v.x); o.y = f2bf(v.y); o.z = f2bf(v.z); o.w = f2bf(v.w);
    ((short4*)xb)[i] = o;
  }
}

// W: [1024][1024] fp32 [k][n] -> Wt: [n][k] bf16 ; z selects which W; also zero ksum
__global__ void transposeW_kernel(const float* __restrict__ Wq, const float* __restrict__ Wk,
                                  const float* __restrict__ Wv, const float* __restrict__ Wo,
                                  short* __restrict__ Wt, short* __restrict__ WoT,
                                  float* __restrict__ ksum) {
  int z = blockIdx.z;
  int t = threadIdx.x;
  if (z == 0 && blockIdx.y == 0 && blockIdx.x < 16)
    ksum[blockIdx.x * 256 + t] = 0.f;            // 64*64 floats
  const float* W = (z == 0) ? Wq : (z == 1) ? Wk : (z == 2) ? Wv : Wo;
  short* dstb = (z < 3) ? (Wt + (size_t)z * 1024 * 1024) : WoT;
  __shared__ float tile[64][69];
  int r = t >> 2, c4 = (t & 3) << 4;
  const float* src = W + (blockIdx.y * 64 + r) * 1024 + blockIdx.x * 64 + c4;
  for (int j = 0; j < 4; ++j) {
    float4 v = ((const float4*)src)[j];
    tile[r][c4 + 4 * j + 0] = v.x;
    tile[r][c4 + 4 * j + 1] = v.y;
    tile[r][c4 + 4 * j + 2] = v.z;
    tile[r][c4 + 4 * j + 3] = v.w;
  }
  __syncthreads();
  __attribute__((aligned(16))) short tmp[16];
  for (int j = 0; j < 16; ++j) tmp[j] = f2bf(tile[c4 + j][r]);
  short* dst = dstb + (blockIdx.x * 64 + r) * 1024 + blockIdx.y * 64 + c4;
  ((int4*)dst)[0] = ((int4*)tmp)[0];
  ((int4*)dst)[1] = ((int4*)tmp)[1];
}

// ---------------- 2/5. 256x256 BK=64 8-phase MFMA GEMM, hoisted addressing ----------------
// 8 waves (2M x 4N), 512 threads, 128 KiB LDS: 2 sets x (A 32K | B 32K).
// Swizzle: LDS 16B slot s of a 128B row holds global slot s^(row&7); since
// row&7 == rl&7 (lane-constant), ds_read addr = hoisted base[set][kk] + row-imm.

#define RA(set, mbase, kk)                                                   \
  _Pragma("unroll") for (int m_ = 0; m_ < 4; ++m_)                           \
    a[m_] = *(const bf16x8*)(baseA##set##kk + ((mbase) + m_) * 2048);

#define RB(set, kk)                                                          \
  _Pragma("unroll") for (int n_ = 0; n_ < 4; ++n_)                           \
    b[n_] = *(const bf16x8*)(baseB##set##kk + n_ * 2048);

#define MF(mbase)                                                            \
  __builtin_amdgcn_s_setprio(1);                                             \
  _Pragma("unroll") for (int m_ = 0; m_ < 4; ++m_)                           \
    _Pragma("unroll") for (int n_ = 0; n_ < 4; ++n_)                         \
      acc[(mbase) + m_][n_] = __builtin_amdgcn_mfma_f32_16x16x32_bf16(       \
          a[m_], b[n_], acc[(mbase) + m_][n_], 0, 0, 0);                     \
  __builtin_amdgcn_s_setprio(0);

// stage one half-tile (h) = 2 gload16 (l=0,1); t = K-tile index
#define STG(Gb, t, h, reg)                                                   \
  gload16((Gb) + (t) * 64 + (h) * 131072 + goff,         (reg) + (h) * 16384 + wq);          \
  gload16((Gb) + (t) * 64 + (h) * 131072 + 65536 + goff, (reg) + (h) * 16384 + 8192 + wq);

template <int MODE>
__global__ __launch_bounds__(512, 2) void gemm256_kernel(
    const short* __restrict__ A, const short* __restrict__ Bt,
    short* __restrict__ q, short* __restrict__ kT, short* __restrict__ vT,
    float* __restrict__ out, const float* __restrict__ bias,
    float* __restrict__ ksum, int nTilesN) {
  __shared__ __align__(16) char smraw[131072];

  int bid = blockIdx.x;
  int xcd = bid & 7, lo = bid >> 3;
  int tn = lo >> 3, tmg = lo & 7;
  int tm = xcd * 8 + tmg;

  int t = threadIdx.x, w = t >> 6, lane = t & 63;
  int rl = lane & 15, kg = lane >> 4;
  int wr = w >> 2, wc = w & 3;

  const short* Ab = A + (size_t)tm * 256 * 1024;
  const short* Bb2 = Bt + (size_t)tn * 256 * 1024;

  // hoisted ds_read bases (lane-constant swizzle term)
  const int rx = rl & 7;
  char* baseA00 = smraw + (wr * 128 + rl) * 128 + (((0 * 4 + kg) ^ rx) << 4);
  char* baseA01 = smraw + (wr * 128 + rl) * 128 + (((1 * 4 + kg) ^ rx) << 4);
  char* baseA10 = baseA00 + 65536;
  char* baseA11 = baseA01 + 65536;
  char* baseB00 = smraw + 32768 + (wc * 64 + rl) * 128 + (((0 * 4 + kg) ^ rx) << 4);
  char* baseB01 = smraw + 32768 + (wc * 64 + rl) * 128 + (((1 * 4 + kg) ^ rx) << 4);
  char* baseB10 = baseB00 + 65536;
  char* baseB11 = baseB01 + 65536;

  // hoisted stage addressing
  int srow = w * 8 + (lane >> 3);                                  // 0..63
  const int goff = srow * 1024 + (((lane & 7) ^ (srow & 7)) << 3); // shorts
  const int wq = w * 1024;                                         // bytes
  char* regA0 = smraw;
  char* regB0 = smraw + 32768;
  char* regA1 = smraw + 65536;
  char* regB1 = smraw + 98304;

  f32x4 acc[8][4] = {};
  bf16x8 a[4], b[4];

  // prologue: tile0 fully + tile1's B h0
  STG(Ab, 0, 0, regA0); STG(Ab, 0, 1, regA0);
  STG(Bb2, 0, 0, regB0); STG(Bb2, 0, 1, regB0);
  STG(Bb2, 1, 0, regB1);
  WAITV(2);
  SBAR();

#pragma unroll 1
  for (int i = 0; i < 8; ++i) {
    int t1 = 2 * i + 1, t2 = 2 * i + 2, t3 = 2 * i + 3;
    // P1
    RA(0, 0, 0); RB(0, 0);
    STG(Bb2, t1, 1, regB1);
    SBAR(); MF(0); SBAR();
    // P2
    RA(0, 4, 0);
    STG(Ab, t1, 0, regA1);
    SBAR(); MF(4); SBAR();
    // P3
    RA(0, 0, 1); RB(0, 1);
    STG(Ab, t1, 1, regA1);
    SBAR(); MF(0); SBAR();
    // P4
    RA(0, 4, 1);
    STG(Bb2, t2, 0, regB0);
    WAITV(2); SBAR(); MF(4); SBAR();
    // P5
    RA(1, 0, 0); RB(1, 0);
    STG(Ab, t2, 0, regA0);
    SBAR(); MF(0); SBAR();
    // P6
    RA(1, 4, 0);
    STG(Ab, t2, 1, regA0);
    SBAR(); MF(4); SBAR();
    // P7
    RA(1, 0, 1); RB(1, 1);
    STG(Bb2, t2, 1, regB0);
    SBAR(); MF(0); SBAR();
    // P8
    RA(1, 4, 1);
    STG(Bb2, t3, 0, regB1);
    WAITV(2); SBAR(); MF(4); SBAR();
  }

  // drain in-flight (garbage tail) stages before LDS reuse
  WAITV(0);
  SBAR();

  if (MODE == 1) {
    // two 128-row fp32 half-passes; swizzled [128][256] f32 tile (128 KiB)
    float* smf = (float*)smraw;
    for (int hp = 0; hp < 2; ++hp) {
      if (wr == hp) {
#pragma unroll
        for (int m = 0; m < 8; ++m)
#pragma unroll
          for (int n = 0; n < 4; ++n)
#pragma unroll
            for (int r = 0; r < 4; ++r) {
              int lrow = m * 16 + kg * 4 + r;
              int col = wc * 64 + n * 16 + rl;
              smf[lrow * 256 + ((((col >> 2) ^ (lrow & 7))) << 2) + (col & 3)] = acc[m][n][r];
            }
      }
      SBAR();
      for (int it = 0; it < 16; ++it) {
        int idx = it * 512 + t;
        int row = idx >> 6, c4 = (idx & 63) << 2;
        float4 v = *(const float4*)&smf[row * 256 + ((((c4 >> 2) ^ (row & 7))) << 2)];
        float4 bv = *(const float4*)&bias[tn * 256 + c4];
        v.x += bv.x; v.y += bv.y; v.z += bv.z; v.w += bv.w;
        *(float4*)&out[(size_t)(tm * 256 + hp * 128 + row) * Dd + tn * 256 + c4] = v;
      }
      SBAR();
    }
    return;
  }

  // MODE 0: stage 256x256 bf16 C tile in LDS (transposed for k/v), coalesced int4 out
  short* smc = (short*)smraw;
  int sec = tn >> 2, tl = tn & 3;   // 0=q 1=k 2=v (4 tn-tiles per section)
#pragma unroll
  for (int m = 0; m < 8; ++m)
#pragma unroll
    for (int n = 0; n < 4; ++n)
#pragma unroll
      for (int r = 0; r < 4; ++r) {
        float v = acc[m][n][r];
        if (sec <= 1) v = v > 0.f ? v + 1.f : __expf(v);   // elu(x)+1
        int row = wr * 128 + m * 16 + kg * 4 + r;
        int col = wc * 64 + n * 16 + rl;
        int rr = (sec == 0) ? row : col;
        int cc = (sec == 0) ? col : row;
        smc[rr * 256 + ((((cc >> 3) ^ (rr & 7))) << 3) + (cc & 7)] = f2bf(v);
      }
  SBAR();
  if (sec == 0) {
    for (int it = 0; it < 16; ++it) {
      int idx = it * 512 + t;
      int row = idx >> 5, c8 = (idx & 31) << 3;
      int4 val = *(const int4*)&smc[row * 256 + ((((c8 >> 3) ^ (row & 7))) << 3)];
      int grow = tm * 256 + row;
      int bI = grow >> 12, n = grow & 4095;
      int g = tl * 256 + c8;
      int h = g >> 6, d0 = g & 63;
      *(int4*)&q[(((size_t)(bI * Hh + h)) * Nn + n) * DHd + d0] = val;
    }
  } else {
    short* dst = (sec == 1) ? kT : vT;
    for (int it = 0; it < 16; ++it) {
      int idx = it * 512 + t;
      int dr = idx >> 5, c8 = (idx & 31) << 3;
      int4 val = *(const int4*)&smc[dr * 256 + ((((c8 >> 3) ^ (dr & 7))) << 3)];
      int g = tl * 256 + dr;
      int h = g >> 6, d = g & 63;
      int grow0 = tm * 256 + c8;
      int bI = grow0 >> 12, n0 = grow0 & 4095;
      *(int4*)&dst[(((size_t)(bI * Hh + h)) * DHd + d) * Nn + n0] = val;
    }
    if (sec == 1) {
      // fused ksum over the staged k-tile [dcol 256][n 256]
      int dcol = t >> 1, half = t & 1;
      float s = 0.f;
      for (int c = half * 128; c < half * 128 + 128; ++c)
        s += bf2f(smc[dcol * 256 + ((((c >> 3) ^ (dcol & 7))) << 3) + (c & 7)]);
      s += __shfl_xor(s, 1);
      if (half == 0) {
        int g = tl * 256 + dcol;
        int h = g >> 6, d = g & 63;
        int bI = (tm * 256) >> 12;
        atomicAdd(&ksum[(bI * Hh + h) * DHd + d], s);
      }
    }
  }
}

// ---------------- 3. kv partials: kvp[bh][8][e][d] fp32 ----------------
__global__ __launch_bounds__(256, 2) void kv_kernel(const short* __restrict__ kT,
                                                    const short* __restrict__ vT,
                                                    float* __restrict__ kvp) {
  __shared__ __align__(16) short smK[64 * 128];
  __shared__ __align__(16) short smV[64 * 128];
  int bh = blockIdx.x, seg = blockIdx.y;
  int t = threadIdx.x;
  int w = t >> 6, lane = t & 63, rl = lane & 15, kg = lane >> 4;
  const short* kb = kT + (size_t)bh * DHd * Nn + seg * 512;
  const short* vb = vT + (size_t)bh * DHd * Nn + seg * 512;
  f32x4 acc[4] = {};
  for (int n0 = 0; n0 < 512; n0 += 128) {
    __syncthreads();
    for (int p = 0; p < 4; ++p) {
      int c = p * 256 + t;
      int row = c >> 4, u = c & 15;
      int off = ((u ^ (row & 15)) << 3);          // pre-swizzled source slot
      gload16(kb + row * Nn + n0 + off, (char*)smK + p * 4096 + w * 1024);
      gload16(vb + row * Nn + n0 + off, (char*)smV + p * 4096 + w * 1024);
    }
    __syncthreads();
    for (int kk = 0; kk < 4; ++kk) {
      int slot = kk * 4 + kg;
      int rowA = w * 16 + rl;
      bf16x8 av = *(const bf16x8*)&smK[rowA * 128 + ((slot ^ (rowA & 15)) << 3)];
      for (int nt = 0; nt < 4; ++nt) {
        int rowB = nt * 16 + rl;
        bf16x8 bv = *(const bf16x8*)&smV[rowB * 128 + ((slot ^ (rowB & 15)) << 3)];
        acc[nt] = __builtin_amdgcn_mfma_f32_16x16x32_bf16(av, bv, acc[nt], 0, 0, 0);
      }
    }
  }
  float* smf = (float*)smK;
  __syncthreads();
  for (int nt = 0; nt < 4; ++nt)
    for (int r = 0; r < 4; ++r)
      smf[(nt * 16 + rl) * 64 + (w * 16 + kg * 4 + r)] = acc[nt][r];
  __syncthreads();
  float* dst = kvp + ((size_t)(bh * 8 + seg)) * 4096;
  for (int i = 0; i < 4; ++i) {
    int idx = i * 256 + t;
    int e = idx >> 4, c4 = (idx & 15) << 2;
    *(float4*)&dst[e * 64 + c4] = *(const float4*)&smf[e * 64 + c4];
  }
}

// combine 8 fp32 partials -> kvT bf16 [bh][e][d]
__global__ void kvc_kernel(const float* __restrict__ kvp, short* __restrict__ kvT) {
  int bh = blockIdx.x, t = threadIdx.x;
  const float* p0 = kvp + (size_t)bh * 8 * 4096;
  for (int rep = 0; rep < 4; ++rep) {
    int idx = rep * 1024 + t * 4;
    float4 s = *(const float4*)&p0[idx];
    for (int j = 1; j < 8; ++j) {
      float4 aa = *(const float4*)&p0[j * 4096 + idx];
      s.x += aa.x; s.y += aa.y; s.z += aa.z; s.w += aa.w;
    }
    short4 o;
    o.x = f2bf(s.x); o.y = f2bf(s.y); o.z = f2bf(s.z); o.w = f2bf(s.w);
    *(short4*)&kvT[(size_t)bh * 4096 + idx] = o;
  }
}

// ---------------- 4. out = (q @ kv) / z ----------------
__global__ __launch_bounds__(256, 2) void attn_kernel(const short* __restrict__ q,
                                                      const short* __restrict__ kvT,
                                                      const float* __restrict__ ksum,
                                                      short* __restrict__ attn) {
  int rb = blockIdx.x, bh = blockIdx.y;
  int b = bh >> 4, h = bh & 15;
  __shared__ float sks[64];
  __shared__ __align__(16) short satt[64 * 64];
  int t = threadIdx.x, w = t >> 6, lane = t & 63, rl = lane & 15, kg = lane >> 4;
  if (t < 64) sks[t] = ksum[bh * 64 + t];
  __syncthreads();
  int row0 = rb * 64 + w * 16;
  const short* qb = q + ((size_t)bh * Nn + row0) * DHd;
  const short* kvb = kvT + (size_t)bh * 4096;
  f32x4 acc[4] = {};
  float zp = 0.f;
  for (int kk = 0; kk < 2; ++kk) {
    int kb = kk * 32 + kg * 8;
    bf16x8 av = *(const bf16x8*)&qb[rl * DHd + kb];
    for (int j = 0; j < 8; ++j) zp += bf2f(av[j]) * sks[kb + j];
    for (int nt = 0; nt < 4; ++nt) {
      bf16x8 bfr = *(const bf16x8*)&kvb[(nt * 16 + rl) * 64 + kb];
      acc[nt] = __builtin_amdgcn_mfma_f32_16x16x32_bf16(av, bfr, acc[nt], 0, 0, 0);
    }
  }
  zp += __shfl_xor(zp, 16);
  zp += __shfl_xor(zp, 32);     // every lane now holds z for row (lane&15)
  float zr[4];
  for (int r = 0; r < 4; ++r) zr[r] = __shfl(zp, kg * 4 + r);
  for (int nt = 0; nt < 4; ++nt)
    for (int r = 0; r < 4; ++r)
      satt[(w * 16 + kg * 4 + r) * 64 + nt * 16 + rl] = f2bf(acc[nt][r] / (zr[r] + 1e-6f));
  __syncthreads();
  for (int i = 0; i < 2; ++i) {
    int idx = i * 256 + t;                 // int4 index over 64x64 shorts
    int row = idx >> 3, c8 = (idx & 7) << 3;
    int n = rb * 64 + row;
    *(int4*)&attn[((size_t)(b * Nn + n)) * 1024 + h * 64 + c8] = *(const int4*)&satt[row * 64 + c8];
  }
}

// ---------------- launch ----------------
extern "C" void kernel_launch(void* const* d_in, const int* in_sizes, int n_in,
                              void* d_out, int out_size, void* d_ws, size_t ws_size,
                              hipStream_t stream) {
  const float* x  = (const float*)d_in[0];
  const float* Wq = (const float*)d_in[1];
  const float* Wk = (const float*)d_in[2];
  const float* Wv = (const float*)d_in[3];
  const float* Wo = (const float*)d_in[4];
  const float* bo = (const float*)d_in[5];
  float* out = (float*)d_out;

  char* ws = (char*)d_ws;
  size_t off = 0;
  auto alloc = [&](size_t bytes) {
    char* p = ws + off;
    off += (bytes + 255) & ~(size_t)255;
    return p;
  };
  short* xb   = (short*)alloc((size_t)Mrows * 1024 * 2);     // 32 MB
  short* Wt   = (short*)alloc((size_t)3072 * 1024 * 2);      // 6 MB
  short* WoT  = (short*)alloc((size_t)1024 * 1024 * 2);      // 2 MB
  short* qb   = (short*)alloc((size_t)64 * Nn * DHd * 2);    // 32 MB  [bh][n][d]
  short* kT   = (short*)alloc((size_t)64 * DHd * Nn * 2);    // 32 MB  [bh][d][n]
  short* vT   = (short*)alloc((size_t)64 * DHd * Nn * 2);    // 32 MB  [bh][d][n]
  float* ksum = (float*)alloc((size_t)64 * 64 * 4);          // fused ksum accumulator
  float* kvp  = (float*)alloc((size_t)64 * 8 * 4096 * 4);    // 8 MB kv partials
  short* kvT  = (short*)alloc((size_t)64 * 4096 * 2);        // [bh][e][d]
  short* attn = (short*)alloc((size_t)Mrows * 1024 * 2);     // 32 MB
  (void)alloc(1 << 20);                                       // pad for benign K over-reads

  convert_x_kernel<<<2048, 256, 0, stream>>>(x, xb);
  transposeW_kernel<<<dim3(16, 16, 4), 256, 0, stream>>>(Wq, Wk, Wv, Wo, Wt, WoT, ksum);

  gemm256_kernel<0><<<768, 512, 0, stream>>>(xb, Wt, qb, kT, vT, nullptr, nullptr, ksum, 12);
  kv_kernel<<<dim3(64, 8), 256, 0, stream>>>(kT, vT, kvp);
  kvc_kernel<<<64, 256, 0, stream>>>(kvp, kvT);
  attn_kernel<<<dim3(64, 64), 256, 0, stream>>>(qb, kvT, ksum, attn);
  gemm256_kernel<1><<<256, 512, 0, stream>>>(attn, WoT, nullptr, nullptr, nullptr, out, bo, nullptr, 4);
}